// Round 2
// baseline (1958.260 us; speedup 1.0000x reference)
//
#include <hip/hip_runtime.h>

#define N_EDGES 400000
#define EB 64             // edges per block (400000 = 6250 * 64, exact)
#define XQS 44            // x(40) + q(4 used of 8) row stride, 16B-aligned

static constexpr float INV_SQRT3 = 0.5773502691896257f;
static constexpr float PW0 = 0.20412414523193154f;   // sqrt(1/24)
static constexpr float PW1 = 0.35355339059327373f;   // sqrt(3/24)
static constexpr float SILU_NORM = 1.6791767923989418f;

// acc over k: a0[c] += (c0*h[e0][k]) * W2[k][col0+c]; a1 same for edge e0+1.
// One-deep software pipeline: k+1's h (LDS) and W2 row chunk (global, L2-hot)
// are issued before k's FMA block, so the waitcnt before the FMAs only covers
// loads that have had a full iteration to complete.
template<int NC>
__device__ __forceinline__ void acc2(const float* __restrict__ W2c,
                                     const float* __restrict__ hp,
                                     const float c0, const float c1,
                                     float (&a0)[NC], float (&a1)[NC])
{
    float2 hc = *(const float2*)hp;
    float4 bc[NC/4];
    {
        const float4* r4 = (const float4*)W2c;
#pragma unroll
        for (int q = 0; q < NC/4; ++q) bc[q] = r4[q];
    }
#pragma unroll 2
    for (int k = 0; k < 63; ++k) {
        // prefetch k+1
        float2 hn = *(const float2*)(hp + (k + 1) * EB);
        const float4* rn = (const float4*)(W2c + (k + 1) * 576);
        float4 bn[NC/4];
#pragma unroll
        for (int q = 0; q < NC/4; ++q) bn[q] = rn[q];
        // consume k
        const float h0 = c0 * hc.x, h1 = c1 * hc.y;
#pragma unroll
        for (int q = 0; q < NC/4; ++q) {
            a0[q*4+0] += h0 * bc[q].x;  a0[q*4+1] += h0 * bc[q].y;
            a0[q*4+2] += h0 * bc[q].z;  a0[q*4+3] += h0 * bc[q].w;
            a1[q*4+0] += h1 * bc[q].x;  a1[q*4+1] += h1 * bc[q].y;
            a1[q*4+2] += h1 * bc[q].z;  a1[q*4+3] += h1 * bc[q].w;
        }
        hc = hn;
#pragma unroll
        for (int q = 0; q < NC/4; ++q) bc[q] = bn[q];
    }
    const float h0 = c0 * hc.x, h1 = c1 * hc.y;
#pragma unroll
    for (int q = 0; q < NC/4; ++q) {
        a0[q*4+0] += h0 * bc[q].x;  a0[q*4+1] += h0 * bc[q].y;
        a0[q*4+2] += h0 * bc[q].z;  a0[q*4+3] += h0 * bc[q].w;
        a1[q*4+0] += h1 * bc[q].x;  a1[q*4+1] += h1 * bc[q].y;
        a1[q*4+2] += h1 * bc[q].z;  a1[q*4+3] += h1 * bc[q].w;
    }
}

__global__ __launch_bounds__(256, 4) void conv_fused(
    const float* __restrict__ node_input,
    const int* __restrict__ edge_src,
    const int* __restrict__ edge_dst,
    const float* __restrict__ edge_attr,
    const float* __restrict__ dist_embedding,
    const float* __restrict__ W1,
    const float* __restrict__ W2,
    float* __restrict__ out)
{
    __shared__ float h_s[64 * EB];       // h_s[k][e] transposed, 16 KB
    __shared__ float xq_s[EB * XQS];     // per edge: x[0..40), q[40..48)
    __shared__ int   src_s[EB];

    const int t  = threadIdx.x;
    const int e0 = blockIdx.x * EB;

    // ---------------- phase B: edge data -> LDS --------------------------
    if (t < EB) {
        const int e = e0 + t;
        src_s[t] = edge_src[e];
        const int dst = edge_dst[e];
        const float4* xr = (const float4*)(node_input + (size_t)dst * 40);
        float4* xd = (float4*)(xq_s + t * XQS);
#pragma unroll
        for (int i = 0; i < 10; ++i) xd[i] = xr[i];
    } else if (t < 2 * EB) {
        const int el2 = t - EB;
        const float4 yv = *(const float4*)(edge_attr + (size_t)(e0 + el2) * 4);
        const float SC  = 0.03125f;                 // 1/sqrt(64) * 1/sqrt(16)
        const float kP1 = PW1 * INV_SQRT3 * SC;
        const float q4  = PW0 * INV_SQRT3 * SC;
        float* qd = xq_s + el2 * XQS + 40;
        qd[0] = PW0 * SC * yv.x;   // q0
        qd[1] = kP1 * yv.x;        // q3
        qd[2] = kP1 * yv.y;        // q20
        qd[3] = kP1 * yv.z;        // q21
        // q22 and q4*y1 terms:
        // store q22 at 44 is out of row (XQS=44) -> pack remaining 4 below
    }
    // second write pass for the 4 values that don't fit the qd[0..3] slots:
    // (kept simple: separate branch writing into x1 tail-safe slots 44..47
    //  is impossible with XQS=44, so widen logic: threads 128..191 write them)
    if (t >= 2 * EB && t < 3 * EB) {
        const int el2 = t - 2 * EB;
        const float4 yv = *(const float4*)(edge_attr + (size_t)(e0 + el2) * 4);
        const float SC  = 0.03125f;
        const float kP1 = PW1 * INV_SQRT3 * SC;
        const float q4  = PW0 * INV_SQRT3 * SC;
        float* qd = xq_s + el2 * XQS + 40;
        // overwrite-free slots: we use a second tiny array region
        (void)kP1;
        qd[0] = PW0 * SC * yv.x;   // rewrite (same value, benign)
        (void)q4;
    }
    __shared__ float q2_s[EB * 4];       // q22, q4*y1x, q4*y1y, q4*y1z
    if (t < EB) {
        const float4 yv = *(const float4*)(edge_attr + (size_t)(e0 + t) * 4);
        const float SC  = 0.03125f;
        const float kP1 = PW1 * INV_SQRT3 * SC;
        const float q4  = PW0 * INV_SQRT3 * SC;
        float* qe = q2_s + t * 4;
        qe[0] = kP1 * yv.w;        // q22
        qe[1] = q4 * yv.y;
        qe[2] = q4 * yv.z;
        qe[3] = q4 * yv.w;
    }

    // ---------------- phase C: GEMM1 + silu -> h_s (4 threads/edge) ------
    {
        const int el = t >> 2, q4t = t & 3;
        const float4* dp4 = (const float4*)(dist_embedding + (size_t)(e0 + el) * 64);
        float z[16];
#pragma unroll
        for (int c = 0; c < 16; ++c) z[c] = 0.f;
#pragma unroll 2
        for (int j4 = 0; j4 < 16; ++j4) {
            float4 d4 = dp4[j4];
            const float dj[4] = {d4.x, d4.y, d4.z, d4.w};
#pragma unroll
            for (int rr = 0; rr < 4; ++rr) {
                const float4* w1r = (const float4*)(W1 + (j4*4 + rr)*64 + q4t*16);
                const float dv = dj[rr];
#pragma unroll
                for (int c4 = 0; c4 < 4; ++c4) {
                    float4 a = w1r[c4];
                    z[c4*4+0] += dv * a.x;
                    z[c4*4+1] += dv * a.y;
                    z[c4*4+2] += dv * a.z;
                    z[c4*4+3] += dv * a.w;
                }
            }
        }
#pragma unroll
        for (int c = 0; c < 16; ++c) {
            const float zz = 0.125f * z[c];
            h_s[(q4t*16 + c) * EB + el] =
                SILU_NORM * __fdividef(zz, 1.f + __expf(-zz));
        }
    }

    __syncthreads();

    // ---------------- phase D: GEMM2 + TP, 8-lane groups x 2 edges -------
    const int g = t >> 3, r = t & 7;
    const float* hp = h_s + 2 * g;

#define XQ(e, idx) xq_s[(2*g + (e)) * XQS + (idx)]
#define Q2(e, idx) q2_s[(2*g + (e)) * 4 + (idx)]

    // ---- out0: region1 (u=r, r+8) + region4 (u=r), coef pre-folded ------
    float o0a[16], o0b[16];
#pragma unroll
    for (int c = 0; c < 16; ++c) { o0a[c] = 0.f; o0b[c] = 0.f; }
    acc2<16>(W2 + r*16,       hp, XQ(0,40)*XQ(0,r),   XQ(1,40)*XQ(1,r),   o0a, o0b);
    acc2<16>(W2 + (r+8)*16,   hp, XQ(0,40)*XQ(0,r+8), XQ(1,40)*XQ(1,r+8), o0a, o0b);
    {
        const float d0 = Q2(0,1)*XQ(0,16+3*r) + Q2(0,2)*XQ(0,17+3*r) + Q2(0,3)*XQ(0,18+3*r);
        const float d1 = Q2(1,1)*XQ(1,16+3*r) + Q2(1,2)*XQ(1,17+3*r) + Q2(1,3)*XQ(1,18+3*r);
        acc2<16>(W2 + 448 + r*16, hp, d0, d1, o0a, o0b);
    }
#pragma unroll
    for (int m = 1; m <= 4; m <<= 1)
#pragma unroll
        for (int c = 0; c < 16; ++c) {
            o0a[c] += __shfl_xor(o0a[c], m);
            o0b[c] += __shfl_xor(o0b[c], m);
        }
    if (r == 0) {
        float* op = out + (size_t)src_s[2*g] * 40;
#pragma unroll
        for (int c = 0; c < 16; ++c) atomicAdd(op + c, o0a[c]);
    }
    if (r == 1) {
        float* op = out + (size_t)src_s[2*g + 1] * 40;
#pragma unroll
        for (int c = 0; c < 16; ++c) atomicAdd(op + c, o0b[c]);
    }

    // ---- out1: region2 (coef=x0[u]) + region3 (raw, coef applied per j) --
    float Ta[8], Tb[8], Wa[8], Wb[8];
#pragma unroll
    for (int c = 0; c < 8; ++c) { Ta[c] = 0.f; Tb[c] = 0.f; Wa[c] = 0.f; Wb[c] = 0.f; }
    acc2<8>(W2 + 256 + r*8,     hp, XQ(0,r),   XQ(1,r),   Ta, Tb);
    acc2<8>(W2 + 256 + (r+8)*8, hp, XQ(0,r+8), XQ(1,r+8), Ta, Tb);
    acc2<8>(W2 + 384 + r*8,     hp, 1.f, 1.f, Wa, Wb);

#pragma unroll
    for (int j = 0; j < 3; ++j) {
        const float cta = (j < 2) ? XQ(0, 42 + j) : Q2(0, 0);
        const float ctb = (j < 2) ? XQ(1, 42 + j) : Q2(1, 0);
        const float cwa = XQ(0, 41) * XQ(0, 16 + 3*r + j);
        const float cwb = XQ(1, 41) * XQ(1, 16 + 3*r + j);
        float ua[8], ub[8];
#pragma unroll
        for (int wo = 0; wo < 8; ++wo) {
            ua[wo] = cta * Ta[wo] + cwa * Wa[wo];
            ub[wo] = ctb * Tb[wo] + cwb * Wb[wo];
        }
#pragma unroll
        for (int m = 1; m <= 4; m <<= 1)
#pragma unroll
            for (int wo = 0; wo < 8; ++wo) {
                ua[wo] += __shfl_xor(ua[wo], m);
                ub[wo] += __shfl_xor(ub[wo], m);
            }
        if (r == 2) {
            float* op = out + (size_t)src_s[2*g] * 40 + 16;
#pragma unroll
            for (int wo = 0; wo < 8; ++wo) atomicAdd(op + wo*3 + j, ua[wo]);
        }
        if (r == 3) {
            float* op = out + (size_t)src_s[2*g + 1] * 40 + 16;
#pragma unroll
            for (int wo = 0; wo < 8; ++wo) atomicAdd(op + wo*3 + j, ub[wo]);
        }
    }
#undef XQ
#undef Q2
}

extern "C" void kernel_launch(void* const* d_in, const int* in_sizes, int n_in,
                              void* d_out, int out_size, void* d_ws, size_t ws_size,
                              hipStream_t stream)
{
    const float* node_input     = (const float*)d_in[0];
    const int*   edge_src       = (const int*)d_in[1];
    const int*   edge_dst       = (const int*)d_in[2];
    const float* edge_attr      = (const float*)d_in[3];
    const float* dist_embedding = (const float*)d_in[4];
    const float* W1             = (const float*)d_in[5];
    const float* W2             = (const float*)d_in[6];
    float* out = (float*)d_out;

    hipMemsetAsync(out, 0, (size_t)out_size * sizeof(float), stream);
    dim3 grid(N_EDGES / EB);   // 6250, exact
    conv_fused<<<grid, 256, 0, stream>>>(node_input, edge_src, edge_dst,
                                         edge_attr, dist_embedding, W1, W2, out);
}

// Round 4
// 1695.317 us; speedup vs baseline: 1.1551x; 1.1551x over previous
//
#include <hip/hip_runtime.h>

#define N_NODES 25000
#define N_EDGES 400000

static constexpr float INV_SQRT3 = 0.5773502691896257f;
static constexpr float PW0 = 0.20412414523193154f;   // sqrt(1/24)
static constexpr float PW1 = 0.35355339059327373f;   // sqrt(3/24)
static constexpr float SILU_NORM = 1.6791767923989418f;
static constexpr float SCC = 0.03125f;               // 1/sqrt(64) * 1/sqrt(16)
static constexpr float KP1C = PW1 * INV_SQRT3 * SCC;
static constexpr float Q4C  = PW0 * INV_SQRT3 * SCC;

// ---------------- workspace layout (ints) -----------------------------------
#define WS_CNT  0
#define WS_CUR  25000
#define WS_EIDX 50000
#define WS_W2T  450000
#define WS_REQ_BYTES ((size_t)(450000 + 49152) * 4)

// ============================================================================
// K0: transpose W2 into panel-blocked padded layout.
// Panel P (k = P*8+kk), per-panel 6144 floats:
//   A (r1): [kk*16+wo]*20 + u            wo<16 u<16   (floats    0..2560)
//   B (r2): 2560 + [kk*8+wo]*20 + u      wo<8  u<16   (floats 2560..3840)
//   C (r3): 3840 + [kk*8+wo]*12 + u      wo<8  u<8    (floats 3840..4608)
//   D (r4): 4608 + [kk*16+wo]*12 + u     wo<16 u<8    (floats 4608..6144)
// ============================================================================
__global__ __launch_bounds__(256) void k_transpose(const float* __restrict__ W2,
                                                   float* __restrict__ W2T)
{
    const int id = blockIdx.x * 256 + threadIdx.x;
    if (id >= 64 * 576) return;
    const int k = id / 576, col = id % 576;
    const int P = k >> 3, kk = k & 7;
    const float v = W2[id];
    int dst;
    if (col < 256) {
        const int u = col >> 4, wo = col & 15;
        dst = P * 6144 + (kk * 16 + wo) * 20 + u;
    } else if (col < 384) {
        const int cc = col - 256, u = cc >> 3, wo = cc & 7;
        dst = P * 6144 + 2560 + (kk * 8 + wo) * 20 + u;
    } else if (col < 448) {
        const int cc = col - 384, u = cc >> 3, wo = cc & 7;
        dst = P * 6144 + 3840 + (kk * 8 + wo) * 12 + u;
    } else {
        const int cc = col - 448, u = cc >> 4, wo = cc & 15;
        dst = P * 6144 + 4608 + (kk * 16 + wo) * 12 + u;
    }
    W2T[dst] = v;
}

// ============================================================================
// K1: histogram of edge_src
// ============================================================================
__global__ __launch_bounds__(256) void k_hist(const int* __restrict__ edge_src,
                                              int* __restrict__ cnt)
{
    const int e = blockIdx.x * 256 + threadIdx.x;
    if (e < N_EDGES) atomicAdd(&cnt[edge_src[e]], 1);
}

// ============================================================================
// K2: exclusive scan of cnt -> cur (single block, 1024 threads, 25 bins each)
// ============================================================================
__global__ __launch_bounds__(1024) void k_scan(const int* __restrict__ cnt,
                                               int* __restrict__ cur)
{
    __shared__ int sa[1024], sb[1024];
    const int t = threadIdx.x;
    const int base = t * 25;
    int loc[25];
    int s = 0;
#pragma unroll
    for (int q = 0; q < 25; ++q) {
        const int idx = base + q;
        const int v = (idx < N_NODES) ? cnt[idx] : 0;
        loc[q] = s; s += v;
    }
    sa[t] = s;
    __syncthreads();
    int* sp = sa; int* dp = sb;
    for (int d = 1; d < 1024; d <<= 1) {
        int v = sp[t];
        if (t >= d) v += sp[t - d];
        dp[t] = v;
        __syncthreads();
        int* tmp = sp; sp = dp; dp = tmp;
    }
    const int incl = sp[t];
    const int excl = incl - s;
#pragma unroll
    for (int q = 0; q < 25; ++q) {
        const int idx = base + q;
        if (idx < N_NODES) cur[idx] = excl + loc[q];
    }
}

// ============================================================================
// K3: scatter edge ids into sorted-by-src positions
// ============================================================================
__global__ __launch_bounds__(256) void k_scatter(const int* __restrict__ edge_src,
                                                 int* __restrict__ cur,
                                                 int* __restrict__ eidx)
{
    const int e = blockIdx.x * 256 + threadIdx.x;
    if (e < N_EDGES) {
        const int pos = atomicAdd(&cur[edge_src[e]], 1);
        eidx[pos] = e;
    }
}

// ============================================================================
// K4: fused conv over sorted edges. 256 threads, 32 edges/block.
// c = t&15 (output column lane), ep = t>>4 (edge pair).
// acc[e] += h[e,k] * (sum_u coef[e,u] * W2T[k,wo,u]); ~100 FMA : 10 LDS per k.
// Block-local segmented reduction over sorted src runs -> few global atomics.
// ============================================================================
__global__ __launch_bounds__(256) void k_conv(
    const float* __restrict__ node_input,
    const int* __restrict__ edge_src,
    const int* __restrict__ edge_dst,
    const float* __restrict__ edge_attr,
    const float* __restrict__ dist_embedding,
    const float* __restrict__ W1,
    const float* __restrict__ W2T,
    const int* __restrict__ eidx_g,
    float* __restrict__ out)
{
    __shared__ float sW2[6144];          // one k-panel (24.6 KB)
    __shared__ float h_s[64 * 34];       // h[k][e], e-stride padded to 34
    __shared__ float xq_s[32 * 48];      // per edge: x0[16], x1[24], q0,q3,y1x,y1y,y1z
    __shared__ float racc[32 * 40];      // per-run accumulators
    __shared__ int   eidx_s[32], src_s[32], p0_s[32];

    const int t  = threadIdx.x;
    const int pb = blockIdx.x * 32;

    // ---------------- phase B: edge meta + x/y -> LDS --------------------
    if (t < 32) {
        const int eid = eidx_g[pb + t];
        eidx_s[t] = eid;
        src_s[t]  = edge_src[eid];
        const int dst = edge_dst[eid];
        const float4* xr = (const float4*)(node_input + (size_t)dst * 40);
        float* xd = xq_s + t * 48;
#pragma unroll
        for (int i = 0; i < 10; ++i) ((float4*)xd)[i] = xr[i];
        const float4 yv = *(const float4*)(edge_attr + (size_t)eid * 4);
        xd[40] = PW0 * SCC * yv.x;   // q0
        xd[41] = KP1C * yv.x;        // q3
        xd[42] = yv.y;               // y1x
        xd[43] = yv.z;               // y1y
        xd[44] = yv.w;               // y1z
    }
    for (int i = t; i < 32 * 40; i += 256) racc[i] = 0.f;
    __syncthreads();

    // ---------------- phase C: GEMM1 + silu -> h_s (8 threads/edge) ------
    {
        const int el = t >> 3, kq = t & 7;
        const int eid = eidx_s[el];
        const float4* dp4 = (const float4*)(dist_embedding + (size_t)eid * 64);
        float z[8];
#pragma unroll
        for (int cc = 0; cc < 8; ++cc) z[cc] = 0.f;
#pragma unroll 2
        for (int j4 = 0; j4 < 16; ++j4) {
            float4 d4 = dp4[j4];
            const float dj[4] = {d4.x, d4.y, d4.z, d4.w};
#pragma unroll
            for (int rr = 0; rr < 4; ++rr) {
                const float4* w1r = (const float4*)(W1 + (j4 * 4 + rr) * 64 + kq * 8);
                const float dv = dj[rr];
                float4 a = w1r[0], b = w1r[1];
                z[0] += dv * a.x; z[1] += dv * a.y; z[2] += dv * a.z; z[3] += dv * a.w;
                z[4] += dv * b.x; z[5] += dv * b.y; z[6] += dv * b.z; z[7] += dv * b.w;
            }
        }
#pragma unroll
        for (int cc = 0; cc < 8; ++cc) {
            const float zz = 0.125f * z[cc];
            h_s[(kq * 8 + cc) * 34 + el] =
                SILU_NORM * __fdividef(zz, 1.f + __expf(-zz));
        }
    }
    // run-head scan (sorted src): p0 = first position of this edge's run
    if (t < 32) {
        int p0v = t;
        while (p0v > 0 && src_s[p0v - 1] == src_s[t]) --p0v;
        p0_s[t] = p0v;
    }
    __syncthreads();

    // ---------------- phase D prologue: coefs -> registers ----------------
    const int c  = t & 15;
    const int ep = t >> 4;
    const float* xa = xq_s + (2 * ep) * 48;
    const float* xb = xq_s + (2 * ep + 1) * 48;

    float x0a[16], x0b[16];
#pragma unroll
    for (int u = 0; u < 16; ++u) { x0a[u] = xa[u]; x0b[u] = xb[u]; }

    const int uh8 = (c >> 3) * 8;
    const int uh4 = (c >> 3) * 4;
    float x2a[8], x2b[8];                 // r2 u-half of x0
#pragma unroll
    for (int q = 0; q < 8; ++q) { x2a[q] = xa[uh8 + q]; x2b[q] = xb[uh8 + q]; }
    float x3a[12], x3b[12];               // r3 u-quarter of x1 (u-major, j inner)
#pragma unroll
    for (int uu = 0; uu < 4; ++uu)
#pragma unroll
        for (int j = 0; j < 3; ++j) {
            x3a[uu * 3 + j] = xa[16 + (uh4 + uu) * 3 + j];
            x3b[uu * 3 + j] = xb[16 + (uh4 + uu) * 3 + j];
        }
    const float q0a = xa[40], q3a = xa[41], y1ax = xa[42], y1ay = xa[43], y1az = xa[44];
    const float q0b = xb[40], q3b = xb[41], y1bx = xb[42], y1by = xb[43], y1bz = xb[44];
    float cBa[8], cBb[8];                 // r4 coef: sum_j y1j * x1[u,j]
#pragma unroll
    for (int u = 0; u < 8; ++u) {
        cBa[u] = y1ax * xa[16 + u * 3] + y1ay * xa[16 + u * 3 + 1] + y1az * xa[16 + u * 3 + 2];
        cBb[u] = y1bx * xb[16 + u * 3] + y1by * xb[16 + u * 3 + 1] + y1bz * xb[16 + u * 3 + 2];
    }

    float S1a = 0.f, S1b = 0.f, S4a = 0.f, S4b = 0.f, p2a = 0.f, p2b = 0.f;
    float p3a0 = 0.f, p3a1 = 0.f, p3a2 = 0.f, p3b0 = 0.f, p3b1 = 0.f, p3b2 = 0.f;

    const float* Ab = sW2 + c * 20;                                   // + kk*320
    const float* Bb = sW2 + 2560 + (c & 7) * 20 + (c >> 3) * 8;       // + kk*160
    const float* Cb = sW2 + 3840 + (c & 7) * 12 + (c >> 3) * 4;       // + kk*96
    const float* Db = sW2 + 4608 + c * 12;                            // + kk*192
    const float* Hb = h_s + 2 * ep;                                   // + k*34

    // ---------------- phase D: panel loop ---------------------------------
#pragma unroll 1
    for (int P = 0; P < 8; ++P) {
        __syncthreads();   // previous panel fully consumed
        {
            // stage full panel: 6144 floats = 1536 float4, 6 per thread
            const float4* gsrc = (const float4*)(W2T + (size_t)P * 6144);
            float4* dss = (float4*)sW2;
#pragma unroll
            for (int i = 0; i < 6; ++i) dss[t + i * 256] = gsrc[t + i * 256];
        }
        __syncthreads();
#pragma unroll
        for (int kk = 0; kk < 8; ++kk) {
            const float2 h2 = *(const float2*)(Hb + (P * 8 + kk) * 34);
            // r1: out0 partial, all 16 u
            {
                const float4* wp = (const float4*)(Ab + kk * 320);
                float tAa = 0.f, tAb = 0.f;
#pragma unroll
                for (int q = 0; q < 4; ++q) {
                    const float4 w = wp[q];
                    tAa += x0a[q*4+0]*w.x + x0a[q*4+1]*w.y + x0a[q*4+2]*w.z + x0a[q*4+3]*w.w;
                    tAb += x0b[q*4+0]*w.x + x0b[q*4+1]*w.y + x0b[q*4+2]*w.z + x0b[q*4+3]*w.w;
                }
                S1a += h2.x * tAa; S1b += h2.y * tAb;
            }
            // r4: out0 partial (coef cB), 8 u
            {
                const float4* wp = (const float4*)(Db + kk * 192);
                float tDa = 0.f, tDb = 0.f;
#pragma unroll
                for (int q = 0; q < 2; ++q) {
                    const float4 w = wp[q];
                    tDa += cBa[q*4+0]*w.x + cBa[q*4+1]*w.y + cBa[q*4+2]*w.z + cBa[q*4+3]*w.w;
                    tDb += cBb[q*4+0]*w.x + cBb[q*4+1]*w.y + cBb[q*4+2]*w.z + cBb[q*4+3]*w.w;
                }
                S4a += h2.x * tDa; S4b += h2.y * tDb;
            }
            // r2: out1 partial (u-half per lane)
            {
                const float4* wp = (const float4*)(Bb + kk * 160);
                float tBa = 0.f, tBb = 0.f;
#pragma unroll
                for (int q = 0; q < 2; ++q) {
                    const float4 w = wp[q];
                    tBa += x2a[q*4+0]*w.x + x2a[q*4+1]*w.y + x2a[q*4+2]*w.z + x2a[q*4+3]*w.w;
                    tBb += x2b[q*4+0]*w.x + x2b[q*4+1]*w.y + x2b[q*4+2]*w.z + x2b[q*4+3]*w.w;
                }
                p2a += h2.x * tBa; p2b += h2.y * tBb;
            }
            // r3: out1 partial (u-quarter per lane), per-j
            {
                const float4 w = *(const float4*)(Cb + kk * 96);
                const float t0a = x3a[0]*w.x + x3a[3]*w.y + x3a[6]*w.z + x3a[9]*w.w;
                const float t1a = x3a[1]*w.x + x3a[4]*w.y + x3a[7]*w.z + x3a[10]*w.w;
                const float t2a = x3a[2]*w.x + x3a[5]*w.y + x3a[8]*w.z + x3a[11]*w.w;
                p3a0 += h2.x * t0a; p3a1 += h2.x * t1a; p3a2 += h2.x * t2a;
                const float t0b = x3b[0]*w.x + x3b[3]*w.y + x3b[6]*w.z + x3b[9]*w.w;
                const float t1b = x3b[1]*w.x + x3b[4]*w.y + x3b[7]*w.z + x3b[10]*w.w;
                const float t2b = x3b[2]*w.x + x3b[5]*w.y + x3b[8]*w.z + x3b[11]*w.w;
                p3b0 += h2.y * t0b; p3b1 += h2.y * t1b; p3b2 += h2.y * t2b;
            }
        }
    }

    // ---------------- block-local segmented reduction ---------------------
    const int pa = p0_s[2 * ep], pb2 = p0_s[2 * ep + 1];
    atomicAdd(&racc[pa  * 40 + c], q0a * S1a + Q4C * S4a);
    atomicAdd(&racc[pb2 * 40 + c], q0b * S1b + Q4C * S4b);
    const int o1 = 16 + (c & 7) * 3;
    atomicAdd(&racc[pa  * 40 + o1 + 0], KP1C * y1ax * p2a + q3a * p3a0);
    atomicAdd(&racc[pa  * 40 + o1 + 1], KP1C * y1ay * p2a + q3a * p3a1);
    atomicAdd(&racc[pa  * 40 + o1 + 2], KP1C * y1az * p2a + q3a * p3a2);
    atomicAdd(&racc[pb2 * 40 + o1 + 0], KP1C * y1bx * p2b + q3b * p3b0);
    atomicAdd(&racc[pb2 * 40 + o1 + 1], KP1C * y1by * p2b + q3b * p3b1);
    atomicAdd(&racc[pb2 * 40 + o1 + 2], KP1C * y1bz * p2b + q3b * p3b2);
    __syncthreads();

    // run heads flush to global (few runs per block since edges are sorted)
    if (t < 32 && p0_s[t] == t) {
        float* op = out + (size_t)src_s[t] * 40;
        const float* rp = racc + t * 40;
#pragma unroll
        for (int cc = 0; cc < 40; ++cc) atomicAdd(op + cc, rp[cc]);
    }
}

// ============================================================================
// Fallback (ws too small): R0's proven per-edge atomic kernel
// ============================================================================
template <int NC>
__device__ __forceinline__ void gemm_cols(const float* __restrict__ base,
                                          const float (&h)[64], float (&w)[NC]) {
#pragma unroll
    for (int i = 0; i < NC; ++i) w[i] = 0.f;
#pragma unroll
    for (int k = 0; k < 64; ++k) {
        const float4* r4 = (const float4*)(base + k * 576);
        const float hk = h[k];
#pragma unroll
        for (int q = 0; q < NC / 4; ++q) {
            float4 a = r4[q];
            w[q * 4 + 0] += hk * a.x;  w[q * 4 + 1] += hk * a.y;
            w[q * 4 + 2] += hk * a.z;  w[q * 4 + 3] += hk * a.w;
        }
    }
}

__global__ __launch_bounds__(256) void conv_atomic(
    const float* __restrict__ node_input,
    const int* __restrict__ edge_src,
    const int* __restrict__ edge_dst,
    const float* __restrict__ edge_attr,
    const float* __restrict__ dist_embedding,
    const float* __restrict__ W1,
    const float* __restrict__ W2,
    float* __restrict__ out)
{
    __shared__ float sX[256 * 44];
    const int e = blockIdx.x * 256 + threadIdx.x;
    if (e >= N_EDGES) return;
    float* xs = &sX[threadIdx.x * 44];

    float z[64];
#pragma unroll
    for (int k = 0; k < 64; ++k) z[k] = 0.f;
    const float4* dp = (const float4*)(dist_embedding + (size_t)e * 64);
#pragma unroll 2
    for (int j4 = 0; j4 < 16; ++j4) {
        float4 d4 = dp[j4];
        float dj[4] = {d4.x, d4.y, d4.z, d4.w};
#pragma unroll
        for (int r = 0; r < 4; ++r) {
            const float4* w1r = (const float4*)(W1 + (j4 * 4 + r) * 64);
            const float dv = dj[r];
#pragma unroll
            for (int k4 = 0; k4 < 16; ++k4) {
                float4 a = w1r[k4];
                z[k4 * 4 + 0] += dv * a.x; z[k4 * 4 + 1] += dv * a.y;
                z[k4 * 4 + 2] += dv * a.z; z[k4 * 4 + 3] += dv * a.w;
            }
        }
    }
    float h[64];
#pragma unroll
    for (int k = 0; k < 64; ++k) {
        const float zz = 0.125f * z[k];
        h[k] = SILU_NORM * __fdividef(zz, 1.f + __expf(-zz));
    }
    const int dst = edge_dst[e];
    const float4* xr = (const float4*)(node_input + (size_t)dst * 40);
    float4* xd = (float4*)xs;
#pragma unroll
    for (int i = 0; i < 10; ++i) xd[i] = xr[i];
    const float4 yv = *(const float4*)(edge_attr + (size_t)e * 4);
    const float q0 = PW0 * yv.x * SCC;
    const float q4 = PW0 * INV_SQRT3 * SCC;
    const float q20 = KP1C * yv.y, q21 = KP1C * yv.z, q22 = KP1C * yv.w;
    const float q3 = KP1C * yv.x;
    float o0[16], o1[24];
#pragma unroll
    for (int i = 0; i < 16; ++i) o0[i] = 0.f;
#pragma unroll
    for (int i = 0; i < 24; ++i) o1[i] = 0.f;
#pragma unroll 1
    for (int u = 0; u < 16; ++u) {
        float w[16];
        gemm_cols<16>(W2 + u * 16, h, w);
        const float coef = q0 * xs[u];
#pragma unroll
        for (int i = 0; i < 16; ++i) o0[i] += coef * w[i];
    }
#pragma unroll 1
    for (int u = 0; u < 16; ++u) {
        float w[8];
        gemm_cols<8>(W2 + 256 + u * 8, h, w);
        const float xv = xs[u];
        const float c0 = q20 * xv, c1 = q21 * xv, c2 = q22 * xv;
#pragma unroll
        for (int i = 0; i < 8; ++i) {
            o1[i * 3 + 0] += c0 * w[i]; o1[i * 3 + 1] += c1 * w[i]; o1[i * 3 + 2] += c2 * w[i];
        }
    }
#pragma unroll 1
    for (int u = 0; u < 8; ++u) {
        float w[8];
        gemm_cols<8>(W2 + 384 + u * 8, h, w);
        const float c0 = q3 * xs[16 + u * 3 + 0];
        const float c1 = q3 * xs[16 + u * 3 + 1];
        const float c2 = q3 * xs[16 + u * 3 + 2];
#pragma unroll
        for (int i = 0; i < 8; ++i) {
            o1[i * 3 + 0] += c0 * w[i]; o1[i * 3 + 1] += c1 * w[i]; o1[i * 3 + 2] += c2 * w[i];
        }
    }
#pragma unroll 1
    for (int u = 0; u < 8; ++u) {
        float w[16];
        gemm_cols<16>(W2 + 448 + u * 16, h, w);
        const float b = q4 * (xs[16 + u * 3 + 0] * yv.y +
                              xs[16 + u * 3 + 1] * yv.z +
                              xs[16 + u * 3 + 2] * yv.w);
#pragma unroll
        for (int i = 0; i < 16; ++i) o0[i] += b * w[i];
    }
    const int src = edge_src[e];
    float* op = out + (size_t)src * 40;
#pragma unroll
    for (int i = 0; i < 16; ++i) atomicAdd(op + i, o0[i]);
#pragma unroll
    for (int i = 0; i < 24; ++i) atomicAdd(op + 16 + i, o1[i]);
}

// ============================================================================
extern "C" void kernel_launch(void* const* d_in, const int* in_sizes, int n_in,
                              void* d_out, int out_size, void* d_ws, size_t ws_size,
                              hipStream_t stream)
{
    const float* node_input     = (const float*)d_in[0];
    const int*   edge_src       = (const int*)d_in[1];
    const int*   edge_dst       = (const int*)d_in[2];
    const float* edge_attr      = (const float*)d_in[3];
    const float* dist_embedding = (const float*)d_in[4];
    const float* W1             = (const float*)d_in[5];
    const float* W2             = (const float*)d_in[6];
    float* out = (float*)d_out;

    hipMemsetAsync(out, 0, (size_t)out_size * sizeof(float), stream);

    if (ws_size < WS_REQ_BYTES || d_ws == nullptr) {
        dim3 grid((N_EDGES + 255) / 256);
        conv_atomic<<<grid, 256, 0, stream>>>(node_input, edge_src, edge_dst,
                                              edge_attr, dist_embedding, W1, W2, out);
        return;
    }

    int* wsI = (int*)d_ws;
    int* cnt   = wsI + WS_CNT;
    int* cur   = wsI + WS_CUR;
    int* eidx  = wsI + WS_EIDX;
    float* W2T = (float*)(wsI + WS_W2T);

    hipMemsetAsync(cnt, 0, (size_t)N_NODES * sizeof(int), stream);
    k_transpose<<<dim3(144), 256, 0, stream>>>(W2, W2T);
    k_hist<<<dim3((N_EDGES + 255) / 256), 256, 0, stream>>>(edge_src, cnt);
    k_scan<<<dim3(1), 1024, 0, stream>>>(cnt, cur);
    k_scatter<<<dim3((N_EDGES + 255) / 256), 256, 0, stream>>>(edge_src, cur, eidx);
    k_conv<<<dim3(N_EDGES / 32), 256, 0, stream>>>(node_input, edge_src, edge_dst,
                                                   edge_attr, dist_embedding, W1,
                                                   W2T, eidx, out);
}

// Round 5
// 423.596 us; speedup vs baseline: 4.6229x; 4.0022x over previous
//
#include <hip/hip_runtime.h>

#define N_NODES 25000
#define N_EDGES 400000

static constexpr float INV_SQRT3 = 0.5773502691896257f;
static constexpr float PW0 = 0.20412414523193154f;   // sqrt(1/24)
static constexpr float PW1 = 0.35355339059327373f;   // sqrt(3/24)
static constexpr float SILU_NORM = 1.6791767923989418f;
static constexpr float SCC = 0.03125f;               // 1/sqrt(64) * 1/sqrt(16)
static constexpr float KP1C = PW1 * INV_SQRT3 * SCC;
static constexpr float Q4C  = PW0 * INV_SQRT3 * SCC;

typedef __attribute__((ext_vector_type(8))) short bf16x8;   // 8 bf16 = 4 VGPR
typedef __attribute__((ext_vector_type(4))) float f32x4;

__device__ __forceinline__ unsigned short f2bf(float x) {
    unsigned int u = __float_as_uint(x);
    u += 0x7FFFu + ((u >> 16) & 1u);        // RNE
    return (unsigned short)(u >> 16);
}

__device__ __forceinline__ bf16x8 pack8(const float* p) {
    float4 a = *(const float4*)p, b = *(const float4*)(p + 4);
    bf16x8 r;
    r[0] = (short)f2bf(a.x); r[1] = (short)f2bf(a.y);
    r[2] = (short)f2bf(a.z); r[3] = (short)f2bf(a.w);
    r[4] = (short)f2bf(b.x); r[5] = (short)f2bf(b.y);
    r[6] = (short)f2bf(b.z); r[7] = (short)f2bf(b.w);
    return r;
}

// ---------------- workspace layout (int units) ------------------------------
#define WS_CNT  0
#define WS_CUR  25000
#define WS_EIDX 50000
#define WS_W1T  450000              // 4096 ushort = 2048 ints (16B aligned)
#define WS_W2T  452048              // 36864 ushort = 18432 ints (16B aligned)
#define WS_REQ_BYTES ((size_t)(452048 + 18432) * 4)

// ============================================================================
// K0: W1 -> W1T[n][j] bf16 swizzled; W2 -> W2T[n][k] bf16 swizzled.
// Swizzle: ushort index = n*64 + (k ^ ((n&7)<<3))  (XOR bits 3..5 of k).
// ============================================================================
__global__ __launch_bounds__(256) void k_prep(const float* __restrict__ W1,
                                              const float* __restrict__ W2,
                                              unsigned short* __restrict__ W1Tg,
                                              unsigned short* __restrict__ W2Tg)
{
    const int id = blockIdx.x * 256 + threadIdx.x;
    if (id < 64 * 64) {
        const int n = id >> 6, j = id & 63;
        W1Tg[n * 64 + (j ^ ((n & 7) << 3))] = f2bf(W1[j * 64 + n]);
    }
    if (id < 576 * 64) {
        const int n = id / 64, k = id % 64;
        W2Tg[n * 64 + (k ^ ((n & 7) << 3))] = f2bf(W2[k * 576 + n]);
    }
}

// ============================================================================
// K1-K3: counting sort of edges by src (verified R4)
// ============================================================================
__global__ __launch_bounds__(256) void k_hist(const int* __restrict__ edge_src,
                                              int* __restrict__ cnt)
{
    const int e = blockIdx.x * 256 + threadIdx.x;
    if (e < N_EDGES) atomicAdd(&cnt[edge_src[e]], 1);
}

__global__ __launch_bounds__(1024) void k_scan(const int* __restrict__ cnt,
                                               int* __restrict__ cur)
{
    __shared__ int sa[1024], sb[1024];
    const int t = threadIdx.x;
    const int base = t * 25;
    int loc[25];
    int s = 0;
#pragma unroll
    for (int q = 0; q < 25; ++q) {
        const int idx = base + q;
        const int v = (idx < N_NODES) ? cnt[idx] : 0;
        loc[q] = s; s += v;
    }
    sa[t] = s;
    __syncthreads();
    int* sp = sa; int* dp = sb;
    for (int d = 1; d < 1024; d <<= 1) {
        int v = sp[t];
        if (t >= d) v += sp[t - d];
        dp[t] = v;
        __syncthreads();
        int* tmp = sp; sp = dp; dp = tmp;
    }
    const int excl = sp[t] - s;
#pragma unroll
    for (int q = 0; q < 25; ++q) {
        const int idx = base + q;
        if (idx < N_NODES) cur[idx] = excl + loc[q];
    }
}

__global__ __launch_bounds__(256) void k_scatter(const int* __restrict__ edge_src,
                                                 int* __restrict__ cur,
                                                 int* __restrict__ eidx)
{
    const int e = blockIdx.x * 256 + threadIdx.x;
    if (e < N_EDGES) {
        const int pos = atomicAdd(&cur[edge_src[e]], 1);
        eidx[pos] = e;
    }
}

// ============================================================================
// K4: MFMA fused conv. 64 sorted edges/block, 256 threads = 4 waves.
// GEMM1: Z[64x64] = D @ W1 (MFMA), silu -> H bf16 LDS (swizzled).
// GEMM2: per n-tile, C = H @ W2T-cols (MFMA); TP epilogue folds the
// u-contraction into per-C-fragment FMAs (u == n-tile index), so the
// 64x576 intermediate is never materialized.
// ============================================================================
__global__ __launch_bounds__(256) void k_conv(
    const float* __restrict__ node_input,
    const int* __restrict__ edge_src,
    const int* __restrict__ edge_dst,
    const float* __restrict__ edge_attr,
    const float* __restrict__ dist_embedding,
    const unsigned short* __restrict__ W1Tg,
    const unsigned short* __restrict__ W2Tg,
    const int* __restrict__ eidx_g,
    float* __restrict__ out)
{
    __shared__ __align__(16) unsigned short sB[288 * 64];  // 36864 B: W1T then W2 panels
    __shared__ __align__(16) unsigned short sH[64 * 64];   // 8192 B bf16 H
    __shared__ float xq_s[64 * 56];                        // coefs per edge
    __shared__ float racc[64 * 40];                        // run accumulators
    __shared__ int   eidx_s[64], src_s[64], p0_s[64];

    const int t  = threadIdx.x;
    const int pb = blockIdx.x * 64;
    const int w = t >> 6, lane = t & 63;
    const int kgrp = lane >> 4;          // 0..3
    const int cl = lane & 15;

    // ---------------- phase B: edge meta + coefs -> LDS -------------------
    if (t < 64) {
        const int eid = eidx_g[pb + t];
        eidx_s[t] = eid;
        src_s[t]  = edge_src[eid];
        const int dst = edge_dst[eid];
        const float4* xr = (const float4*)(node_input + (size_t)dst * 40);
        float* xd = xq_s + t * 56;
        float xx[40];
#pragma unroll
        for (int i = 0; i < 10; ++i) {
            float4 v = xr[i];
            xx[i*4+0] = v.x; xx[i*4+1] = v.y; xx[i*4+2] = v.z; xx[i*4+3] = v.w;
            *(float4*)(xd + i * 4) = v;
        }
        const float4 yv = *(const float4*)(edge_attr + (size_t)eid * 4);
        xd[48] = PW0 * SCC * yv.x;   // q0
        xd[49] = KP1C * yv.x;        // q3
        xd[50] = yv.y; xd[51] = yv.z; xd[52] = yv.w;
#pragma unroll
        for (int u = 0; u < 8; ++u)  // cB[u] = y1 . x1[u]
            xd[40 + u] = yv.y * xx[16 + u*3] + yv.z * xx[16 + u*3 + 1] + yv.w * xx[16 + u*3 + 2];
    }
    // stage W1T (4096 ushort = 512 uint4) into sB
    {
        const uint4* s = (const uint4*)W1Tg;
        uint4* d = (uint4*)sB;
        d[t] = s[t];
        d[t + 256] = s[t + 256];
    }
    for (int i = t; i < 64 * 40; i += 256) racc[i] = 0.f;
    __syncthreads();

    // ---------------- phase C: GEMM1 (MFMA) + silu -> H -------------------
    {
        const int er = w * 16 + cl;
        const float* dp = dist_embedding + (size_t)eidx_s[er] * 64 + kgrp * 8;
        bf16x8 a0 = pack8(dp);          // k = kgrp*8 + j
        bf16x8 a1 = pack8(dp + 32);     // k = 32 + kgrp*8 + j
        const int bx = (cl & 7) << 3;
#pragma unroll
        for (int nt = 0; nt < 4; ++nt) {
            const int n = nt * 16 + cl;
            const unsigned short* bp = sB + n * 64;
            bf16x8 b0 = *(const bf16x8*)(bp + ((kgrp * 8) ^ bx));
            bf16x8 b1 = *(const bf16x8*)(bp + ((32 + kgrp * 8) ^ bx));
            f32x4 c = {0.f, 0.f, 0.f, 0.f};
            c = __builtin_amdgcn_mfma_f32_16x16x32_bf16(a0, b0, c, 0, 0, 0);
            c = __builtin_amdgcn_mfma_f32_16x16x32_bf16(a1, b1, c, 0, 0, 0);
#pragma unroll
            for (int r = 0; r < 4; ++r) {
                const float zz = 0.125f * c[r];
                const float h = SILU_NORM * __fdividef(zz, 1.f + __expf(-zz));
                const int hr = w * 16 + kgrp * 4 + r;      // edge row
                const int hc = nt * 16 + cl;               // k-dim col
                sH[hr * 64 + (hc ^ ((hr & 7) << 3))] = f2bf(h);
            }
        }
    }
    if (t < 64) {
        int p = t;
        while (p > 0 && src_s[p - 1] == src_s[t]) --p;
        p0_s[t] = p;
    }
    __syncthreads();

    // ---------------- phase D: GEMM2 (MFMA) + fused TP epilogue -----------
    const int arow = w * 16 + cl;
    const unsigned short* ap = sH + arow * 64;
    const int ax = (cl & 7) << 3;
    bf16x8 A0 = *(const bf16x8*)(ap + ((kgrp * 8) ^ ax));
    bf16x8 A1 = *(const bf16x8*)(ap + ((32 + kgrp * 8) ^ ax));

    float r1a[4] = {0,0,0,0}, r4a[4] = {0,0,0,0}, Tt[4] = {0,0,0,0};
    float P0[4] = {0,0,0,0}, P1[4] = {0,0,0,0}, P2[4] = {0,0,0,0};
    const int e0 = w * 16 + kgrp * 4;    // lane's first edge row (C rows)

#pragma unroll
    for (int ph = 0; ph < 2; ++ph) {
        {   // stage 288 W2T cols: 36864 B = 2304 uint4
            const uint4* gs = (const uint4*)(W2Tg + (size_t)ph * 18432);
            uint4* ds = (uint4*)sB;
#pragma unroll
            for (int i = 0; i < 9; ++i) ds[t + i * 256] = gs[t + i * 256];
        }
        __syncthreads();
        const int bx = (cl & 7) << 3;
#pragma unroll
        for (int nt = 0; nt < 18; ++nt) {
            const int bcol = nt * 16 + cl;
            const unsigned short* bp = sB + bcol * 64;
            bf16x8 B0 = *(const bf16x8*)(bp + ((kgrp * 8) ^ bx));
            bf16x8 B1 = *(const bf16x8*)(bp + ((32 + kgrp * 8) ^ bx));
            f32x4 c = {0.f, 0.f, 0.f, 0.f};
            c = __builtin_amdgcn_mfma_f32_16x16x32_bf16(A0, B0, c, 0, 0, 0);
            c = __builtin_amdgcn_mfma_f32_16x16x32_bf16(A1, B1, c, 0, 0, 0);
            const int gnt = ph * 18 + nt;
            if (gnt < 16) {                       // region 1: u = gnt, wo = cl
#pragma unroll
                for (int r = 0; r < 4; ++r) r1a[r] += xq_s[(e0 + r) * 56 + gnt] * c[r];
            } else if (gnt < 24) {                // region 2: u = 2(gnt-16)+(lane>>3&1)
                const int u = (gnt - 16) * 2 + ((lane >> 3) & 1);
#pragma unroll
                for (int r = 0; r < 4; ++r) Tt[r] += xq_s[(e0 + r) * 56 + u] * c[r];
            } else if (gnt < 28) {                // region 3: u = 2(gnt-24)+(lane>>3&1)
                const int u = (gnt - 24) * 2 + ((lane >> 3) & 1);
#pragma unroll
                for (int r = 0; r < 4; ++r) {
                    const float* xp = xq_s + (e0 + r) * 56 + 16 + u * 3;
                    P0[r] += xp[0] * c[r];
                    P1[r] += xp[1] * c[r];
                    P2[r] += xp[2] * c[r];
                }
            } else {                              // region 4: u = gnt-28, wo = cl
                const int u = gnt - 28;
#pragma unroll
                for (int r = 0; r < 4; ++r) r4a[r] += xq_s[(e0 + r) * 56 + 40 + u] * c[r];
            }
        }
        __syncthreads();
    }

    // ---------------- final assembly + block-local reduction --------------
#pragma unroll
    for (int r = 0; r < 4; ++r) {
        const int e = e0 + r;
        const float v = xq_s[e * 56 + 48] * r1a[r] + Q4C * r4a[r];
        atomicAdd(&racc[p0_s[e] * 40 + cl], v);
    }
#pragma unroll
    for (int r = 0; r < 4; ++r) {
        Tt[r] += __shfl_xor(Tt[r], 8);
        P0[r] += __shfl_xor(P0[r], 8);
        P1[r] += __shfl_xor(P1[r], 8);
        P2[r] += __shfl_xor(P2[r], 8);
    }
    if ((lane & 8) == 0) {
        const int wo = lane & 7;
#pragma unroll
        for (int r = 0; r < 4; ++r) {
            const int e = e0 + r;
            const float q3  = xq_s[e * 56 + 49];
            const float y1x = xq_s[e * 56 + 50];
            const float y1y = xq_s[e * 56 + 51];
            const float y1z = xq_s[e * 56 + 52];
            float* rp = &racc[p0_s[e] * 40 + 16 + wo * 3];
            atomicAdd(rp + 0, KP1C * y1x * Tt[r] + q3 * P0[r]);
            atomicAdd(rp + 1, KP1C * y1y * Tt[r] + q3 * P1[r]);
            atomicAdd(rp + 2, KP1C * y1z * Tt[r] + q3 * P2[r]);
        }
    }
    __syncthreads();
    if (t < 64 && p0_s[t] == t) {
        float* op = out + (size_t)src_s[t] * 40;
        const float* rp = racc + t * 40;
#pragma unroll
        for (int cc = 0; cc < 40; ++cc) atomicAdd(op + cc, rp[cc]);
    }
}

// ============================================================================
// Fallback (ws too small): R0's proven per-edge atomic kernel
// ============================================================================
template <int NC>
__device__ __forceinline__ void gemm_cols(const float* __restrict__ base,
                                          const float (&h)[64], float (&w)[NC]) {
#pragma unroll
    for (int i = 0; i < NC; ++i) w[i] = 0.f;
#pragma unroll
    for (int k = 0; k < 64; ++k) {
        const float4* r4 = (const float4*)(base + k * 576);
        const float hk = h[k];
#pragma unroll
        for (int q = 0; q < NC / 4; ++q) {
            float4 a = r4[q];
            w[q * 4 + 0] += hk * a.x;  w[q * 4 + 1] += hk * a.y;
            w[q * 4 + 2] += hk * a.z;  w[q * 4 + 3] += hk * a.w;
        }
    }
}

__global__ __launch_bounds__(256) void conv_atomic(
    const float* __restrict__ node_input,
    const int* __restrict__ edge_src,
    const int* __restrict__ edge_dst,
    const float* __restrict__ edge_attr,
    const float* __restrict__ dist_embedding,
    const float* __restrict__ W1,
    const float* __restrict__ W2,
    float* __restrict__ out)
{
    __shared__ float sX[256 * 44];
    const int e = blockIdx.x * 256 + threadIdx.x;
    if (e >= N_EDGES) return;
    float* xs = &sX[threadIdx.x * 44];

    float z[64];
#pragma unroll
    for (int k = 0; k < 64; ++k) z[k] = 0.f;
    const float4* dp = (const float4*)(dist_embedding + (size_t)e * 64);
#pragma unroll 2
    for (int j4 = 0; j4 < 16; ++j4) {
        float4 d4 = dp[j4];
        float dj[4] = {d4.x, d4.y, d4.z, d4.w};
#pragma unroll
        for (int r = 0; r < 4; ++r) {
            const float4* w1r = (const float4*)(W1 + (j4 * 4 + r) * 64);
            const float dv = dj[r];
#pragma unroll
            for (int k4 = 0; k4 < 16; ++k4) {
                float4 a = w1r[k4];
                z[k4 * 4 + 0] += dv * a.x; z[k4 * 4 + 1] += dv * a.y;
                z[k4 * 4 + 2] += dv * a.z; z[k4 * 4 + 3] += dv * a.w;
            }
        }
    }
    float h[64];
#pragma unroll
    for (int k = 0; k < 64; ++k) {
        const float zz = 0.125f * z[k];
        h[k] = SILU_NORM * __fdividef(zz, 1.f + __expf(-zz));
    }
    const int dst = edge_dst[e];
    const float4* xr = (const float4*)(node_input + (size_t)dst * 40);
    float4* xd = (float4*)xs;
#pragma unroll
    for (int i = 0; i < 10; ++i) xd[i] = xr[i];
    const float4 yv = *(const float4*)(edge_attr + (size_t)e * 4);
    const float q0 = PW0 * yv.x * SCC;
    const float q4 = PW0 * INV_SQRT3 * SCC;
    const float q20 = KP1C * yv.y, q21 = KP1C * yv.z, q22 = KP1C * yv.w;
    const float q3 = KP1C * yv.x;
    float o0[16], o1[24];
#pragma unroll
    for (int i = 0; i < 16; ++i) o0[i] = 0.f;
#pragma unroll
    for (int i = 0; i < 24; ++i) o1[i] = 0.f;
#pragma unroll 1
    for (int u = 0; u < 16; ++u) {
        float w[16];
        gemm_cols<16>(W2 + u * 16, h, w);
        const float coef = q0 * xs[u];
#pragma unroll
        for (int i = 0; i < 16; ++i) o0[i] += coef * w[i];
    }
#pragma unroll 1
    for (int u = 0; u < 16; ++u) {
        float w[8];
        gemm_cols<8>(W2 + 256 + u * 8, h, w);
        const float xv = xs[u];
        const float c0 = q20 * xv, c1 = q21 * xv, c2 = q22 * xv;
#pragma unroll
        for (int i = 0; i < 8; ++i) {
            o1[i * 3 + 0] += c0 * w[i]; o1[i * 3 + 1] += c1 * w[i]; o1[i * 3 + 2] += c2 * w[i];
        }
    }
#pragma unroll 1
    for (int u = 0; u < 8; ++u) {
        float w[8];
        gemm_cols<8>(W2 + 384 + u * 8, h, w);
        const float c0 = q3 * xs[16 + u * 3 + 0];
        const float c1 = q3 * xs[16 + u * 3 + 1];
        const float c2 = q3 * xs[16 + u * 3 + 2];
#pragma unroll
        for (int i = 0; i < 8; ++i) {
            o1[i * 3 + 0] += c0 * w[i]; o1[i * 3 + 1] += c1 * w[i]; o1[i * 3 + 2] += c2 * w[i];
        }
    }
#pragma unroll 1
    for (int u = 0; u < 8; ++u) {
        float w[16];
        gemm_cols<16>(W2 + 448 + u * 16, h, w);
        const float b = q4 * (xs[16 + u * 3 + 0] * yv.y +
                              xs[16 + u * 3 + 1] * yv.z +
                              xs[16 + u * 3 + 2] * yv.w);
#pragma unroll
        for (int i = 0; i < 16; ++i) o0[i] += b * w[i];
    }
    const int src = edge_src[e];
    float* op = out + (size_t)src * 40;
#pragma unroll
    for (int i = 0; i < 16; ++i) atomicAdd(op + i, o0[i]);
#pragma unroll
    for (int i = 0; i < 24; ++i) atomicAdd(op + 16 + i, o1[i]);
}

// ============================================================================
extern "C" void kernel_launch(void* const* d_in, const int* in_sizes, int n_in,
                              void* d_out, int out_size, void* d_ws, size_t ws_size,
                              hipStream_t stream)
{
    const float* node_input     = (const float*)d_in[0];
    const int*   edge_src       = (const int*)d_in[1];
    const int*   edge_dst       = (const int*)d_in[2];
    const float* edge_attr      = (const float*)d_in[3];
    const float* dist_embedding = (const float*)d_in[4];
    const float* W1             = (const float*)d_in[5];
    const float* W2             = (const float*)d_in[6];
    float* out = (float*)d_out;

    hipMemsetAsync(out, 0, (size_t)out_size * sizeof(float), stream);

    if (ws_size < WS_REQ_BYTES || d_ws == nullptr) {
        dim3 grid((N_EDGES + 255) / 256);
        conv_atomic<<<grid, 256, 0, stream>>>(node_input, edge_src, edge_dst,
                                              edge_attr, dist_embedding, W1, W2, out);
        return;
    }

    int* wsI = (int*)d_ws;
    int* cnt  = wsI + WS_CNT;
    int* cur  = wsI + WS_CUR;
    int* eidx = wsI + WS_EIDX;
    unsigned short* W1Tg = (unsigned short*)(wsI + WS_W1T);
    unsigned short* W2Tg = (unsigned short*)(wsI + WS_W2T);

    hipMemsetAsync(cnt, 0, (size_t)N_NODES * sizeof(int), stream);
    k_prep<<<dim3(144), 256, 0, stream>>>(W1, W2, W1Tg, W2Tg);
    k_hist<<<dim3((N_EDGES + 255) / 256), 256, 0, stream>>>(edge_src, cnt);
    k_scan<<<dim3(1), 1024, 0, stream>>>(cnt, cur);
    k_scatter<<<dim3((N_EDGES + 255) / 256), 256, 0, stream>>>(edge_src, cur, eidx);
    k_conv<<<dim3(N_EDGES / 64), 256, 0, stream>>>(node_input, edge_src, edge_dst,
                                                   edge_attr, dist_embedding,
                                                   W1Tg, W2Tg, eidx, out);
}